// Round 1
// baseline (67.802 us; speedup 1.0000x reference)
//
#include <hip/hip_runtime.h>

// Zoom: out[b,c,t,f] = w*x[..., floor(f*k/n)] + (1-w)*x[..., floor(f*k/n)+1]
// Shape [8,16,256,1024] fp32; k, n are runtime device scalars (k=2, n=3 here).
// Memory-bound: ~134 MB write + ~90 MB read -> target ~36 us @ 6.3 TB/s.

constexpr int F = 1024;          // last-dim size from reference shape
constexpr int VEC = 4;           // outputs per thread
constexpr int BLOCK = F / VEC;   // 256 threads: one block covers one full row

__global__ __launch_bounds__(BLOCK) void zoom_kernel(
    const float* __restrict__ x,
    const int* __restrict__ kp,
    const int* __restrict__ np_,
    float* __restrict__ out,
    int nrows) {
  const int k = kp[0];
  const int n = np_[0];

  const int f0 = threadIdx.x * VEC;

  // Loop-invariant interpolation coefficients for this thread's 4 columns.
  int  idx0[VEC], idx1[VEC];
  float w0[VEC], w1[VEC];
#pragma unroll
  for (int j = 0; j < VEC; ++j) {
    const int f   = f0 + j;
    const int pos = f * k;          // integer numerator of f*k/n
    const int id  = pos / n;        // floor(f*k/n)
    const int rem = pos - id * n;
    const float w = 1.0f - (float)rem / (float)n;  // matches reference op order
    const bool v0 = id < F;
    const bool v1 = (id + 1) < F;
    w0[j]   = v0 ? w : 0.0f;
    w1[j]   = v1 ? (1.0f - w) : 0.0f;
    idx0[j] = v0 ? id : 0;                      // clamped; weight already zeroed
    idx1[j] = v1 ? (id + 1) : (F - 1);
  }

  for (int row = blockIdx.x; row < nrows; row += gridDim.x) {
    const float* __restrict__ xr = x + (size_t)row * F;
    float o[VEC];
#pragma unroll
    for (int j = 0; j < VEC; ++j) {
      const float a = xr[idx0[j]];
      const float b = xr[idx1[j]];
      o[j] = w0[j] * a + w1[j] * b;
    }
    float4 v;
    v.x = o[0]; v.y = o[1]; v.z = o[2]; v.w = o[3];
    *reinterpret_cast<float4*>(out + (size_t)row * F + f0) = v;
  }
}

extern "C" void kernel_launch(void* const* d_in, const int* in_sizes, int n_in,
                              void* d_out, int out_size, void* d_ws, size_t ws_size,
                              hipStream_t stream) {
  const float* x  = (const float*)d_in[0];
  const int*   kp = (const int*)d_in[1];
  const int*   np_ = (const int*)d_in[2];
  float* out = (float*)d_out;

  const int total = in_sizes[0];        // 8*16*256*1024
  const int nrows = total / F;          // 32768

  // 2048 blocks = 8 blocks/CU * 256 CUs; grid-stride 16 rows per block.
  const int grid = (nrows < 2048) ? nrows : 2048;
  zoom_kernel<<<grid, BLOCK, 0, stream>>>(x, kp, np_, out, nrows);
}